// Round 6
// baseline (301.247 us; speedup 1.0000x reference)
//
#include <hip/hip_runtime.h>
#include <hip/hip_bf16.h>
#include <math.h>

#define N_NODES 8192
#define N_EDGES 16384
#define N_E3    1024
#define NGRAPH  256
#define NPG     32
#define SLOPE   (11.0f/48.0f)
#define BN_EPS  1e-5f

__device__ __forceinline__ float rrelu(float v){ return v >= 0.f ? v : SLOPE*v; }
__device__ __forceinline__ float sigm(float v){ return 1.f/(1.f+__expf(-v)); }

typedef __attribute__((ext_vector_type(8))) short short8v;
typedef __attribute__((ext_vector_type(4))) float f32x4;

__device__ __forceinline__ short f2bf(float f) {
  __hip_bfloat16 b = __float2bfloat16(f);
  return *reinterpret_cast<short*>(&b);
}
__device__ __forceinline__ float bf2f(short s) {
  unsigned int u = ((unsigned int)(unsigned short)s) << 16;
  return __uint_as_float(u);
}

// ================= split-bf16 MFMA GEMM ==================
// C[M,J] = act(preA(A)[M,K] @ W[J,K]^T + bias), fp32-grade precision:
// A and W split hi/lo bf16; acc += a_hi*w_hi + a_lo*w_hi + a_hi*w_lo.
// Wb layout: hi plane [J*K], lo plane at Wb + J*K.
// Block 256 thr = 4 waves; tile 64Mx64J; wave w owns rows [bm*64+w*16,+16).
// PRE: 0 none; 1 scatter-mean: rrelu(v/max(q0[row],1)+q1[k]); 2 BN(q0..q3)
template<int PRE, int ACT>
__device__ __forceinline__ void mgemm_body(
    const float* __restrict__ A, const short* __restrict__ Wb,
    const float* __restrict__ bias,
    const float* __restrict__ q0, const float* __restrict__ q1,
    const float* __restrict__ q2, const float* __restrict__ q3,
    const int* __restrict__ rowidx,
    float* __restrict__ C, int M, int K, int J, int blk) {
  int t = threadIdx.x;
  int lane = t & 63, wv = t >> 6;
  int jt = J >> 6;
  int bm = blk / jt, bj = blk % jt;
  int n0 = (bm << 6) + (wv << 4);
  int j0 = bj << 6;
  int row = n0 + (lane & 15);
  int arow = rowidx ? rowidx[row] : row;
  int kb0 = (lane >> 4) * 8;
  size_t szJK = (size_t)J * K;

  f32x4 acc[4] = {{0.f,0.f,0.f,0.f},{0.f,0.f,0.f,0.f},{0.f,0.f,0.f,0.f},{0.f,0.f,0.f,0.f}};

  float pre_dn = 1.f;
  if (PRE == 1) pre_dn = 1.f / fmaxf(q0[row], 1.f);

  for (int k0 = 0; k0 < K; k0 += 32) {
    int kb = k0 + kb0;
    const float* ap = A + (size_t)arow * K + kb;
    float4 v0 = *(const float4*)ap;
    float4 v1 = *(const float4*)(ap + 4);
    if (PRE == 1) {
      float4 b0 = *(const float4*)(q1 + kb);
      float4 b1 = *(const float4*)(q1 + kb + 4);
      v0.x = rrelu(v0.x*pre_dn + b0.x); v0.y = rrelu(v0.y*pre_dn + b0.y);
      v0.z = rrelu(v0.z*pre_dn + b0.z); v0.w = rrelu(v0.w*pre_dn + b0.w);
      v1.x = rrelu(v1.x*pre_dn + b1.x); v1.y = rrelu(v1.y*pre_dn + b1.y);
      v1.z = rrelu(v1.z*pre_dn + b1.z); v1.w = rrelu(v1.w*pre_dn + b1.w);
    } else if (PRE == 2) {
      float4 m0 = *(const float4*)(q0 + kb), m1 = *(const float4*)(q0 + kb + 4);
      float4 s0 = *(const float4*)(q1 + kb), s1 = *(const float4*)(q1 + kb + 4);
      float4 g0 = *(const float4*)(q2 + kb), g1 = *(const float4*)(q2 + kb + 4);
      float4 h0 = *(const float4*)(q3 + kb), h1 = *(const float4*)(q3 + kb + 4);
      v0.x = (v0.x-m0.x)*rsqrtf(s0.x+BN_EPS)*g0.x + h0.x;
      v0.y = (v0.y-m0.y)*rsqrtf(s0.y+BN_EPS)*g0.y + h0.y;
      v0.z = (v0.z-m0.z)*rsqrtf(s0.z+BN_EPS)*g0.z + h0.z;
      v0.w = (v0.w-m0.w)*rsqrtf(s0.w+BN_EPS)*g0.w + h0.w;
      v1.x = (v1.x-m1.x)*rsqrtf(s1.x+BN_EPS)*g1.x + h1.x;
      v1.y = (v1.y-m1.y)*rsqrtf(s1.y+BN_EPS)*g1.y + h1.y;
      v1.z = (v1.z-m1.z)*rsqrtf(s1.z+BN_EPS)*g1.z + h1.z;
      v1.w = (v1.w-m1.w)*rsqrtf(s1.w+BN_EPS)*g1.w + h1.w;
    }
    short8v ah, al;
    {
      float vv[8] = {v0.x,v0.y,v0.z,v0.w,v1.x,v1.y,v1.z,v1.w};
      #pragma unroll
      for (int u = 0; u < 8; u++) {
        short h = f2bf(vv[u]);
        ah[u] = h;
        al[u] = f2bf(vv[u] - bf2f(h));
      }
    }
    #pragma unroll
    for (int jf = 0; jf < 4; jf++) {
      const short* wp = Wb + (size_t)(j0 + jf*16 + (lane & 15)) * K + kb;
      short8v wh = *(const short8v*)wp;
      short8v wl = *(const short8v*)(wp + szJK);
      acc[jf] = __builtin_amdgcn_mfma_f32_16x16x32_bf16(ah, wh, acc[jf], 0, 0, 0);
      acc[jf] = __builtin_amdgcn_mfma_f32_16x16x32_bf16(al, wh, acc[jf], 0, 0, 0);
      acc[jf] = __builtin_amdgcn_mfma_f32_16x16x32_bf16(ah, wl, acc[jf], 0, 0, 0);
    }
  }
  int r0 = (bm << 6) + (wv << 4) + ((lane >> 4) << 2);
  #pragma unroll
  for (int jf = 0; jf < 4; jf++) {
    int col = j0 + jf*16 + (lane & 15);
    float bv = bias ? bias[col] : 0.f;
    #pragma unroll
    for (int r = 0; r < 4; r++) {
      float o = acc[jf][r] + bv;
      if (ACT == 1) o = rrelu(o);
      C[(size_t)(r0 + r) * J + col] = o;
    }
  }
}

// single GEMM + optional zero-tail blocks (folds the sbuf memset)
template<int PRE, int ACT>
__global__ __launch_bounds__(256) void mgemm_k(
    const float* __restrict__ A, const short* __restrict__ Wb, const float* __restrict__ bias,
    const float* __restrict__ q0, const float* __restrict__ q1,
    const float* __restrict__ q2, const float* __restrict__ q3,
    const int* __restrict__ rowidx,
    float* __restrict__ C, int M, int K, int J,
    int nblk, float* __restrict__ zptr, int zcount) {
  int blk = blockIdx.x;
  if (blk >= nblk) {
    int zb = blk - nblk;
    float4 z4 = make_float4(0.f,0.f,0.f,0.f);
    for (int i = zb*256 + (int)threadIdx.x; i*4 < zcount; i += 16*256)
      ((float4*)zptr)[i] = z4;
    return;
  }
  mgemm_body<PRE,ACT>(A, Wb, bias, q0, q1, q2, q3, rowidx, C, M, K, J, blk);
}

// dual GEMM: side0 (PRE0) = gi from sbuf, side1 (PRE1v) = gh from node state
template<int PRE0, int PRE1v>
__global__ __launch_bounds__(256) void mgemm2_k(
    const float* __restrict__ A0, const short* __restrict__ W0, const float* __restrict__ b0,
    const float* __restrict__ q00, const float* __restrict__ q01,
    float* __restrict__ C0, int M0, int K0, int J0, int nblk0,
    const float* __restrict__ A1, const short* __restrict__ W1, const float* __restrict__ b1,
    float* __restrict__ C1, int M1, int K1, int J1) {
  if ((int)blockIdx.x < nblk0)
    mgemm_body<PRE0,0>(A0, W0, b0, q00, q01, nullptr, nullptr, nullptr, C0, M0, K0, J0, blockIdx.x);
  else
    mgemm_body<PRE1v,0>(A1, W1, b1, nullptr, nullptr, nullptr, nullptr, nullptr, C1, M1, K1, J1, blockIdx.x - nblk0);
}

// ================= small kernels =================
__global__ void bn_stats_k(const float* __restrict__ X, int nrow, int F,
                           float* __restrict__ mean, float* __restrict__ var) {
  int f = blockIdx.x, t = threadIdx.x;
  __shared__ float s1[256], s2[256];
  float a = 0.f, b = 0.f;
  for (int n = t; n < nrow; n += 256) {
    float v = X[(size_t)n * F + f];
    a += v; b += v * v;
  }
  s1[t] = a; s2[t] = b; __syncthreads();
  for (int w = 128; w > 0; w >>= 1) {
    if (t < w) { s1[t] += s1[t+w]; s2[t] += s2[t+w]; }
    __syncthreads();
  }
  if (t == 0) {
    float m = s1[0] / (float)nrow;
    mean[f] = m;
    var[f]  = s2[0] / (float)nrow - m * m;
  }
}

// merged node + edge embed
__global__ void embed_k(const float* __restrict__ x,
                        const float* __restrict__ mean, const float* __restrict__ var,
                        const float* __restrict__ g, const float* __restrict__ b,
                        const float* __restrict__ Wn, const float* __restrict__ bnode,
                        float* __restrict__ nodeA,
                        const float* __restrict__ eattr,
                        const float* __restrict__ We, const float* __restrict__ be,
                        float* __restrict__ ea12) {
  if (blockIdx.x < 2048) {
    int idx = blockIdx.x * 256 + threadIdx.x;
    int n = idx >> 6, o = idx & 63;
    float acc = bnode[o];
    #pragma unroll
    for (int i = 0; i < 8; i++) {
      float xn = (x[n*8+i] - mean[i]) * rsqrtf(var[i] + BN_EPS) * g[i] + b[i];
      acc += xn * Wn[i*64 + o];
    }
    nodeA[idx] = rrelu(acc);
  } else {
    int idx = (blockIdx.x - 2048) * 256 + threadIdx.x;
    if (idx >= N_EDGES * 12) return;
    int e = idx / 12, j = idx - e * 12;
    float acc = be[j];
    #pragma unroll
    for (int k = 0; k < 19; k++) acc += eattr[e*19+k] * We[k*12 + j];
    ea12[idx] = rrelu(acc);
  }
}

__device__ __forceinline__ void store_split(short* hi, short* lo, int idx, float v) {
  short h = f2bf(v);
  hi[idx] = h;
  lo[idx] = f2bf(v - bf2f(h));
}

// packs: split-bf16 weights [J,K] (hi plane, lo plane at +J*K) + fp32 Wfold + zero cnt
__global__ void pack_k(const float* __restrict__ Wnn1,
                       const float* __restrict__ Wih1, const float* __restrict__ Whh1,
                       const float* __restrict__ Wc1,  const float* __restrict__ Wc2,
                       const float* __restrict__ Wnn2,
                       const float* __restrict__ Wih2, const float* __restrict__ Whh2,
                       const float* __restrict__ Ws_ih, const float* __restrict__ Ws_hh,
                       short* __restrict__ Wz1b,
                       short* __restrict__ Wih1b, short* __restrict__ Whh1b,
                       short* __restrict__ Wc1Tb, short* __restrict__ Wc2Tb,
                       short* __restrict__ W2fb,
                       short* __restrict__ Wih2b, short* __restrict__ Whh2b,
                       float* __restrict__ Wfold,
                       float* __restrict__ cnt1, float* __restrict__ cnt2) {
  int idx = blockIdx.x * 256 + threadIdx.x;
  if (idx < 49152) {  // Wz1b [768][64]: jj=k*64+o, i
    int jj = idx >> 6, i = idx & 63;
    int k = jj >> 6, o = jj & 63;
    store_split(Wz1b, Wz1b + 49152, idx, Wnn1[k*4096 + i*64 + o]);
  }
  if (idx < 12288) {
    store_split(Wih1b, Wih1b + 12288, idx, Wih1[idx]);
    store_split(Whh1b, Whh1b + 12288, idx, Whh1[idx]);
  }
  if (idx < 8192) {   // Wc1Tb [128][64]
    int o = idx >> 6, i = idx & 63;
    store_split(Wc1Tb, Wc1Tb + 8192, idx, Wc1[i*128 + o]);
  }
  if (idx < 16384) {  // Wc2Tb [128][128]
    int o = idx >> 7, i = idx & 127;
    store_split(Wc2Tb, Wc2Tb + 16384, idx, Wc2[i*128 + o]);
  }
  if (idx < 131072) { // W2fb [1024][128]: r=k*128+o, i
    int r = idx >> 7, i = idx & 127;
    int k = r >> 7, o = r & 127;
    store_split(W2fb, W2fb + 131072, idx, Wnn2[k*16384 + i*128 + o]);
  }
  if (idx < 49152) {
    store_split(Wih2b, Wih2b + 49152, idx, Wih2[idx]);
    store_split(Whh2b, Whh2b + 49152, idx, Whh2[idx]);
  }
  if (idx < 131072) { // Wfold fp32 [256][512]
    int i = idx >> 9, j = idx & 511;
    float v = Ws_ih[(size_t)j*256 + i];
    if (i < 128) v += Ws_hh[(size_t)j*128 + i];
    Wfold[idx] = v;
  }
  if (idx < N_NODES) { cnt1[idx] = 0.f; cnt2[idx] = 0.f; }
}

// per-dst edge counts (iteration-invariant)
__global__ void cnt_k(const int* __restrict__ ei, const int* __restrict__ ei3,
                      float* __restrict__ cnt1, float* __restrict__ cnt2) {
  int idx = blockIdx.x * 256 + threadIdx.x;
  if (idx < N_EDGES) atomicAdd(&cnt1[ei[N_EDGES + idx]], 1.0f);
  if (idx < N_E3) {
    atomicAdd(&cnt2[ei3[N_E3 + idx]], 1.0f);
    atomicAdd(&cnt2[ei3[idx]], 1.0f);
  }
}

// conv1: msg[e,o] = sum_k ea[e,k] * Z[src, k*64+o]; scatter to sbuf
__global__ void conv1_msg_k(const float* __restrict__ Z, const int* __restrict__ ei,
                            const float* __restrict__ ea, float* __restrict__ sbuf) {
  int idx = blockIdx.x * 256 + threadIdx.x;
  if (idx >= N_EDGES * 64) return;
  int e = idx >> 6, o = idx & 63;
  int src = ei[e], dst = ei[N_EDGES + e];
  const float* z = Z + (size_t)src * 768 + o;
  float msg = 0.f;
  #pragma unroll
  for (int k = 0; k < 12; k++) msg += ea[e*12 + k] * z[k*64];
  atomicAdd(&sbuf[dst*64 + o], msg);
}

// conv2: msg[e,o] = sum_k ea3[e&1023,k] * Zg[e, k*128+o]; dst = ei3[(e+1024)&2047]
__global__ void conv2_msg_k(const float* __restrict__ Zg, const int* __restrict__ ei3,
                            const float* __restrict__ ea3, float* __restrict__ sbuf) {
  int idx = blockIdx.x * 256 + threadIdx.x;
  if (idx >= 2*N_E3*128) return;
  int e = idx >> 7, o = idx & 127;
  int eb = e & (N_E3 - 1);
  int dst = ei3[(e + N_E3) & (2*N_E3 - 1)];
  const float* z = Zg + (size_t)e*1024 + o;
  float msg = 0.f;
  #pragma unroll
  for (int k = 0; k < 8; k++) msg += ea3[eb*8 + k] * z[k*128];
  atomicAdd(&sbuf[dst*128 + o], msg);
}

// GRU combine: h = (1-z)*nn + z*h
template<int LOGH>
__global__ void gru_combine_k(const float* __restrict__ gi, const float* __restrict__ gh,
                              float* __restrict__ h) {
  int idx = blockIdx.x * 256 + threadIdx.x;
  const int H = 1 << LOGH;
  if (idx >= N_NODES * H) return;
  int n = idx >> LOGH, f = idx & (H - 1);
  const float* gin = gi + (size_t)n * 3 * H;
  const float* ghn = gh + (size_t)n * 3 * H;
  float r  = sigm(gin[f]        + ghn[f]);
  float z  = sigm(gin[H + f]    + ghn[H + f]);
  float nn = tanhf(gin[2*H + f] + r * ghn[2*H + f]);
  h[idx] = (1.f - z) * nn + z * h[idx];
}

// ---------- Set2Set: 1024 thr/graph, folded weights, step-0 shortcut, x in LDS ----------
__global__ __launch_bounds__(1024) void set2set_k(const float* __restrict__ x,
    const float* __restrict__ Wfold,
    const float* __restrict__ bs_ih, const float* __restrict__ bs_hh,
    float* __restrict__ qpool) {
  int g = blockIdx.x, t = threadIdx.x;
  __shared__ float xs[NPG*128];
  __shared__ float hr[256];
  __shared__ float cbuf[128];
  __shared__ float pbuf[1024];
  __shared__ float abuf[NPG];
  *(float4*)&xs[t*4] = *(const float4*)(x + (size_t)g*NPG*128 + t*4);
  if (t < 128) {
    float gi = bs_ih[t]     + bs_hh[t];
    float gg = bs_ih[256+t] + bs_hh[256+t];
    float go = bs_ih[384+t] + bs_hh[384+t];
    float c0 = sigm(gi) * tanhf(gg);
    cbuf[t] = c0;
    hr[t] = sigm(go) * tanhf(c0);
  }
  __syncthreads();
  #pragma unroll 1
  for (int step = 0; step < 3; step++) {
    {
      int node = t >> 5, s = t & 31;
      const float* xr = xs + node*128 + s*4;
      float p = xr[0]*hr[s*4] + xr[1]*hr[s*4+1] + xr[2]*hr[s*4+2] + xr[3]*hr[s*4+3];
      p += __shfl_down(p, 16, 32); p += __shfl_down(p, 8, 32);
      p += __shfl_down(p, 4, 32);  p += __shfl_down(p, 2, 32);
      p += __shfl_down(p, 1, 32);
      if (s == 0) pbuf[node] = p;
    }
    __syncthreads();
    if (t < NPG) {
      float e = pbuf[t];
      float mx = e;
      for (int o = 16; o > 0; o >>= 1) mx = fmaxf(mx, __shfl_xor(mx, o, 32));
      float ex = __expf(e - mx);
      float den = ex;
      for (int o = 16; o > 0; o >>= 1) den += __shfl_xor(den, o, 32);
      abuf[t] = ex / den;
    }
    __syncthreads();
    if (t < 128) {
      float r = 0.f;
      #pragma unroll 8
      for (int nn = 0; nn < NPG; nn++) r += abuf[nn] * xs[nn*128 + t];
      hr[128 + t] = r;
    }
    __syncthreads();
    if (step == 2) break;
    {
      int j = t & 511, half = t >> 9;
      const float* wp = Wfold + (size_t)(half*128)*512 + j;
      const float* iv = hr + half*128;
      float a0=0.f, a1=0.f, a2=0.f, a3=0.f;
      #pragma unroll 4
      for (int i = 0; i < 128; i += 4) {
        a0 += iv[i]   * wp[(i)  *512];
        a1 += iv[i+1] * wp[(i+1)*512];
        a2 += iv[i+2] * wp[(i+2)*512];
        a3 += iv[i+3] * wp[(i+3)*512];
      }
      pbuf[t] = a0 + a1 + a2 + a3;
    }
    __syncthreads();
    if (t < 128) {
      float gi = pbuf[t]     + pbuf[512+t] + bs_ih[t]     + bs_hh[t];
      float gf = pbuf[128+t] + pbuf[640+t] + bs_ih[128+t] + bs_hh[128+t];
      float gg = pbuf[256+t] + pbuf[768+t] + bs_ih[256+t] + bs_hh[256+t];
      float go = pbuf[384+t] + pbuf[896+t] + bs_ih[384+t] + bs_hh[384+t];
      float ci = sigm(gf) * cbuf[t] + sigm(gi) * tanhf(gg);
      cbuf[t] = ci;
      hr[t] = sigm(go) * tanhf(ci);
    }
    __syncthreads();
  }
  if (t < 256) qpool[g*256 + t] = hr[t];
}

__global__ void yhat_k(const float* __restrict__ feat, const int* __restrict__ ei3,
                       const int* __restrict__ batch, const float* __restrict__ qpool,
                       float* __restrict__ yhat) {
  int idx = blockIdx.x * blockDim.x + threadIdx.x;
  if (idx >= N_E3 * 640) return;
  int e = idx / 640, j = idx - e * 640;
  int s0 = ei3[e], s1 = ei3[N_E3 + e];
  float v;
  if (j < 128)      { v = 0.5f * (feat[s0*128+j] + feat[s1*128+j]); }
  else if (j < 256) { int jj = j-128; v = feat[s0*128+jj] * feat[s1*128+jj]; }
  else if (j < 384) { int jj = j-256; float d = feat[s0*128+jj] - feat[s1*128+jj]; v = d*d; }
  else              { int cbi = batch[s0]; v = qpool[cbi*256 + (j-384)]; }
  yhat[idx] = v;
}

__global__ void final_k(const float* __restrict__ yhat,
                        const float* __restrict__ mean, const float* __restrict__ var,
                        const float* __restrict__ g, const float* __restrict__ b,
                        const float* __restrict__ ea3,
                        const float* __restrict__ Ww, const float* __restrict__ Wb,
                        float* __restrict__ out) {
  int e = blockIdx.x, t = threadIdx.x;
  __shared__ float red[128];
  float av[8];
  #pragma unroll
  for (int k = 0; k < 8; k++) av[k] = ea3[e*8 + k];
  float acc = 0.f;
  for (int j = t; j < 640; j += 128) {
    float yn = (yhat[(size_t)e*640 + j] - mean[j]) * rsqrtf(var[j] + BN_EPS) * g[j] + b[j];
    float wj = 0.f;
    #pragma unroll
    for (int k = 0; k < 8; k++) wj += av[k] * Ww[k*640 + j];
    acc += yn * wj;
  }
  red[t] = acc; __syncthreads();
  for (int w = 64; w > 0; w >>= 1) {
    if (t < w) red[t] += red[t+w];
    __syncthreads();
  }
  if (t == 0) {
    float bb = 0.f;
    #pragma unroll
    for (int k = 0; k < 8; k++) bb += av[k] * Wb[k];
    out[e] = red[0] + bb;
  }
}

extern "C" void kernel_launch(void* const* d_in, const int* in_sizes, int n_in,
                              void* d_out, int out_size, void* d_ws, size_t ws_size,
                              hipStream_t stream) {
  const float* x      = (const float*)d_in[0];
  const int*   ei     = (const int*)  d_in[1];
  const float* eattr  = (const float*)d_in[2];
  const int*   ei3    = (const int*)  d_in[3];
  const float* ea3    = (const float*)d_in[4];
  const int*   batch  = (const int*)  d_in[5];
  const float* bnx_g  = (const float*)d_in[6];
  const float* bnx_b  = (const float*)d_in[7];
  const float* Wn     = (const float*)d_in[8];
  const float* bnode  = (const float*)d_in[9];
  const float* We     = (const float*)d_in[10];
  const float* be     = (const float*)d_in[11];
  const float* Wnn1   = (const float*)d_in[12];
  const float* bias1  = (const float*)d_in[13];
  const float* Wih1   = (const float*)d_in[14];
  const float* Whh1   = (const float*)d_in[15];
  const float* bih1   = (const float*)d_in[16];
  const float* bhh1   = (const float*)d_in[17];
  const float* bnc_g  = (const float*)d_in[18];
  const float* bnc_b  = (const float*)d_in[19];
  const float* Wc1    = (const float*)d_in[20];
  const float* bc1    = (const float*)d_in[21];
  const float* Wc2    = (const float*)d_in[22];
  const float* bc2    = (const float*)d_in[23];
  const float* Wnn2   = (const float*)d_in[24];
  const float* bias2  = (const float*)d_in[25];
  const float* Wih2   = (const float*)d_in[26];
  const float* Whh2   = (const float*)d_in[27];
  const float* bih2   = (const float*)d_in[28];
  const float* bhh2   = (const float*)d_in[29];
  const float* Ws_ih  = (const float*)d_in[30];
  const float* Ws_hh  = (const float*)d_in[31];
  const float* bs_ih  = (const float*)d_in[32];
  const float* bs_hh  = (const float*)d_in[33];
  const float* bno_g  = (const float*)d_in[34];
  const float* bno_b  = (const float*)d_in[35];
  const float* Ww     = (const float*)d_in[36];
  const float* Wb     = (const float*)d_in[37];
  float* out = (float*)d_out;

  // workspace carve-up
  float* W = (float*)d_ws;
  size_t off = 0;
  float* Wfold = W + off; off += 131072;                 // [256][512] fp32
  float* ea12  = W + off; off += (size_t)N_EDGES * 12;
  float* nodeA = W + off; off += (size_t)N_NODES * 64;
  float* sbuf  = W + off; off += (size_t)N_NODES * 128;
  float* cnt1  = W + off; off += (size_t)N_NODES;
  float* cnt2  = W + off; off += (size_t)N_NODES;
  float* y1    = W + off; off += (size_t)N_NODES * 128;
  float* nodeB = W + off; off += (size_t)N_NODES * 128;
  float* Z     = W + off; off += (size_t)N_NODES * 768;  // aliased: gates / Zg
  float* qpool = W + off; off += (size_t)NGRAPH * 256;
  float* yhat  = W + off; off += (size_t)N_E3 * 640;
  float* mean  = W + off; off += 640;
  float* var   = W + off; off += 640;
  // split-bf16 weight packs: each array doubled (hi plane + lo plane)
  short* S = (short*)(W + off);
  size_t soff = 0;
  short* Wz1b  = S + soff; soff += 2*49152;    // [768][64]   x2
  short* Wih1b = S + soff; soff += 2*12288;    // [192][64]   x2
  short* Whh1b = S + soff; soff += 2*12288;
  short* Wc1Tb = S + soff; soff += 2*8192;     // [128][64]   x2
  short* Wc2Tb = S + soff; soff += 2*16384;    // [128][128]  x2
  short* W2fb  = S + soff; soff += 2*131072;   // [1024][128] x2
  short* Wih2b = S + soff; soff += 2*49152;    // [384][128]  x2
  short* Whh2b = S + soff; soff += 2*49152;
  (void)soff; (void)ws_size; (void)in_sizes; (void)n_in; (void)out_size;

  float* gatesI1 = Z;                          // [8192,192]
  float* gatesH1 = Z + (size_t)N_NODES * 192;
  float* gatesI2 = Z;                          // [8192,384]
  float* gatesH2 = Z + (size_t)N_NODES * 384;
  float* Zg      = Z;                          // [2048,1024]

  // 0. one-time packs (+ zero cnt) + counts
  pack_k<<<512, 256, 0, stream>>>(Wnn1, Wih1, Whh1, Wc1, Wc2, Wnn2, Wih2, Whh2, Ws_ih, Ws_hh,
                                  Wz1b, Wih1b, Whh1b, Wc1Tb, Wc2Tb, W2fb, Wih2b, Whh2b,
                                  Wfold, cnt1, cnt2);
  cnt_k<<<(N_EDGES+255)/256, 256, 0, stream>>>(ei, ei3, cnt1, cnt2);

  // 1. embeds
  bn_stats_k<<<8, 256, 0, stream>>>(x, N_NODES, 8, mean, var);
  embed_k<<<2048 + 768, 256, 0, stream>>>(x, mean, var, bnx_g, bnx_b, Wn, bnode, nodeA,
                                          eattr, We, be, ea12);

  // 2. layer-1 x2: Z MFMA-GEMM (+zero sbuf) -> scatter -> dual gate MFMA -> combine
  for (int it = 0; it < 2; it++) {
    mgemm_k<0,0><<<1536 + 16, 256, 0, stream>>>(nodeA, Wz1b, nullptr,
        nullptr, nullptr, nullptr, nullptr, nullptr, Z, N_NODES, 64, 768,
        1536, sbuf, N_NODES*64);
    conv1_msg_k<<<(N_EDGES*64)/256, 256, 0, stream>>>(Z, ei, ea12, sbuf);
    mgemm2_k<1,0><<<768, 256, 0, stream>>>(
        sbuf,  Wih1b, bih1, cnt1, bias1, gatesI1, N_NODES, 64, 192, 384,
        nodeA, Whh1b, bhh1,              gatesH1, N_NODES, 64, 192);
    gru_combine_k<6><<<(N_NODES*64)/256, 256, 0, stream>>>(gatesI1, gatesH1, nodeA);
  }

  // 3. BN (fused) + FC1 + FC2 (MFMA)
  bn_stats_k<<<64, 256, 0, stream>>>(nodeA, N_NODES, 64, mean, var);
  mgemm_k<2,1><<<256, 256, 0, stream>>>(nodeA, Wc1Tb, bc1,
      mean, var, bnc_g, bnc_b, nullptr, y1, N_NODES, 64, 128, 256, nullptr, 0);
  mgemm_k<0,1><<<256, 256, 0, stream>>>(y1, Wc2Tb, bc2,
      nullptr, nullptr, nullptr, nullptr, nullptr, nodeB, N_NODES, 128, 128, 256, nullptr, 0);

  // 4. layer-2 x2: Zg MFMA (row-gather, +zero sbuf) -> scatter -> dual gate MFMA -> combine
  for (int it = 0; it < 2; it++) {
    mgemm_k<0,0><<<512 + 16, 256, 0, stream>>>(nodeB, W2fb, nullptr,
        nullptr, nullptr, nullptr, nullptr, ei3, Zg, 2*N_E3, 128, 1024,
        512, sbuf, N_NODES*128);
    conv2_msg_k<<<(2*N_E3*128)/256, 256, 0, stream>>>(Zg, ei3, ea3, sbuf);
    mgemm2_k<1,0><<<1536, 256, 0, stream>>>(
        sbuf,  Wih2b, bih2, cnt2, bias2, gatesI2, N_NODES, 128, 384, 768,
        nodeB, Whh2b, bhh2,              gatesH2, N_NODES, 128, 384);
    gru_combine_k<7><<<(N_NODES*128)/256, 256, 0, stream>>>(gatesI2, gatesH2, nodeB);
  }

  // 5. set2set
  set2set_k<<<NGRAPH, 1024, 0, stream>>>(nodeB, Wfold, bs_ih, bs_hh, qpool);

  // 6. yhat + BN + weighted sum
  yhat_k<<<(N_E3*640 + 255)/256, 256, 0, stream>>>(nodeB, ei3, batch, qpool, yhat);
  bn_stats_k<<<640, 256, 0, stream>>>(yhat, N_E3, 640, mean, var);
  final_k<<<N_E3, 128, 0, stream>>>(yhat, mean, var, bno_g, bno_b, ea3, Ww, Wb, out);
}

// Round 7
// 232.658 us; speedup vs baseline: 1.2948x; 1.2948x over previous
//
#include <hip/hip_runtime.h>
#include <hip/hip_bf16.h>
#include <math.h>

#define N_NODES 8192
#define N_EDGES 16384
#define N_E3    1024
#define NGRAPH  256
#define NPG     32
#define SLOPE   (11.0f/48.0f)
#define BN_EPS  1e-5f

__device__ __forceinline__ float rrelu(float v){ return v >= 0.f ? v : SLOPE*v; }
__device__ __forceinline__ float sigm(float v){ return 1.f/(1.f+__expf(-v)); }

typedef _Float16 f16;
typedef __attribute__((ext_vector_type(8))) _Float16 half8v;
typedef __attribute__((ext_vector_type(4))) float f32x4;

// ================= f16 MFMA GEMM: C[M,J] = act(preA(A)[M,K] @ Wh[J,K]^T + bias) =====
// Block 256 thr = 4 waves; tile 64Mx64J; wave w owns rows [bm*64+w*16,+16).
// PRE: 0 none; 1 scatter-mean: rrelu(v/max(q0[row],1)+q1[k]); 2 BN(q0..q3)
template<int PRE, int ACT>
__device__ __forceinline__ void mgemm_body(
    const float* __restrict__ A, const f16* __restrict__ Wh,
    const float* __restrict__ bias,
    const float* __restrict__ q0, const float* __restrict__ q1,
    const float* __restrict__ q2, const float* __restrict__ q3,
    const int* __restrict__ rowidx,
    float* __restrict__ C, int M, int K, int J, int blk) {
  int t = threadIdx.x;
  int lane = t & 63, wv = t >> 6;
  int jt = J >> 6;
  int bm = blk / jt, bj = blk % jt;
  int n0 = (bm << 6) + (wv << 4);
  int j0 = bj << 6;
  int row = n0 + (lane & 15);
  int arow = rowidx ? rowidx[row] : row;
  int kb0 = (lane >> 4) * 8;

  f32x4 acc[4] = {{0.f,0.f,0.f,0.f},{0.f,0.f,0.f,0.f},{0.f,0.f,0.f,0.f},{0.f,0.f,0.f,0.f}};

  float pre_dn = 1.f;
  if (PRE == 1) pre_dn = 1.f / fmaxf(q0[row], 1.f);

  for (int k0 = 0; k0 < K; k0 += 32) {
    int kb = k0 + kb0;
    const float* ap = A + (size_t)arow * K + kb;
    float4 v0 = *(const float4*)ap;
    float4 v1 = *(const float4*)(ap + 4);
    if (PRE == 1) {
      float4 b0 = *(const float4*)(q1 + kb);
      float4 b1 = *(const float4*)(q1 + kb + 4);
      v0.x = rrelu(v0.x*pre_dn + b0.x); v0.y = rrelu(v0.y*pre_dn + b0.y);
      v0.z = rrelu(v0.z*pre_dn + b0.z); v0.w = rrelu(v0.w*pre_dn + b0.w);
      v1.x = rrelu(v1.x*pre_dn + b1.x); v1.y = rrelu(v1.y*pre_dn + b1.y);
      v1.z = rrelu(v1.z*pre_dn + b1.z); v1.w = rrelu(v1.w*pre_dn + b1.w);
    } else if (PRE == 2) {
      float4 m0 = *(const float4*)(q0 + kb), m1 = *(const float4*)(q0 + kb + 4);
      float4 s0 = *(const float4*)(q1 + kb), s1 = *(const float4*)(q1 + kb + 4);
      float4 g0 = *(const float4*)(q2 + kb), g1 = *(const float4*)(q2 + kb + 4);
      float4 h0 = *(const float4*)(q3 + kb), h1 = *(const float4*)(q3 + kb + 4);
      v0.x = (v0.x-m0.x)*rsqrtf(s0.x+BN_EPS)*g0.x + h0.x;
      v0.y = (v0.y-m0.y)*rsqrtf(s0.y+BN_EPS)*g0.y + h0.y;
      v0.z = (v0.z-m0.z)*rsqrtf(s0.z+BN_EPS)*g0.z + h0.z;
      v0.w = (v0.w-m0.w)*rsqrtf(s0.w+BN_EPS)*g0.w + h0.w;
      v1.x = (v1.x-m1.x)*rsqrtf(s1.x+BN_EPS)*g1.x + h1.x;
      v1.y = (v1.y-m1.y)*rsqrtf(s1.y+BN_EPS)*g1.y + h1.y;
      v1.z = (v1.z-m1.z)*rsqrtf(s1.z+BN_EPS)*g1.z + h1.z;
      v1.w = (v1.w-m1.w)*rsqrtf(s1.w+BN_EPS)*g1.w + h1.w;
    }
    half8v af;
    af[0]=(f16)v0.x; af[1]=(f16)v0.y; af[2]=(f16)v0.z; af[3]=(f16)v0.w;
    af[4]=(f16)v1.x; af[5]=(f16)v1.y; af[6]=(f16)v1.z; af[7]=(f16)v1.w;
    #pragma unroll
    for (int jf = 0; jf < 4; jf++) {
      const f16* wp = Wh + (size_t)(j0 + jf*16 + (lane & 15)) * K + kb;
      half8v wf = *(const half8v*)wp;
      acc[jf] = __builtin_amdgcn_mfma_f32_16x16x32_f16(af, wf, acc[jf], 0, 0, 0);
    }
  }
  int r0 = (bm << 6) + (wv << 4) + ((lane >> 4) << 2);
  #pragma unroll
  for (int jf = 0; jf < 4; jf++) {
    int col = j0 + jf*16 + (lane & 15);
    float bv = bias ? bias[col] : 0.f;
    #pragma unroll
    for (int r = 0; r < 4; r++) {
      float o = acc[jf][r] + bv;
      if (ACT == 1) o = rrelu(o);
      C[(size_t)(r0 + r) * J + col] = o;
    }
  }
}

// single GEMM + optional zero-tail blocks (folds the sbuf memset)
template<int PRE, int ACT>
__global__ __launch_bounds__(256) void mgemm_k(
    const float* __restrict__ A, const f16* __restrict__ Wh, const float* __restrict__ bias,
    const float* __restrict__ q0, const float* __restrict__ q1,
    const float* __restrict__ q2, const float* __restrict__ q3,
    const int* __restrict__ rowidx,
    float* __restrict__ C, int M, int K, int J,
    int nblk, float* __restrict__ zptr, int zcount) {
  int blk = blockIdx.x;
  if (blk >= nblk) {
    int zb = blk - nblk;
    float4 z4 = make_float4(0.f,0.f,0.f,0.f);
    for (int i = zb*256 + (int)threadIdx.x; i*4 < zcount; i += 16*256)
      ((float4*)zptr)[i] = z4;
    return;
  }
  mgemm_body<PRE,ACT>(A, Wh, bias, q0, q1, q2, q3, rowidx, C, M, K, J, blk);
}

// ============ fused GRU: gates (both matmuls) + combine, writes h ping-pong =========
// grid covers (M/(rows/block)) x (H/64); per block: 64 j-outputs, rows = 16*waves.
// aR/aZ accumulate m@Wih_r + h@Whh_r (fused); aIN = m@Wih_n, aHN = h@Whh_n.
template<int LOGH>
__global__ void gruf_k(const float* __restrict__ sbuf, const float* __restrict__ cnt,
                       const float* __restrict__ mbias,
                       const f16* __restrict__ Wih, const f16* __restrict__ Whh,
                       const float* __restrict__ bih, const float* __restrict__ bhh,
                       const float* __restrict__ hold, float* __restrict__ hnew) {
  const int H = 1 << LOGH;
  const int K = H;
  const int jt = H >> 6;
  int t = threadIdx.x;
  int lane = t & 63, wv = t >> 6;
  int wpb = blockDim.x >> 6;
  int bm = blockIdx.x / jt, bj = blockIdx.x % jt;
  int n0 = bm * (wpb << 4) + (wv << 4);
  int j0 = bj << 6;
  int row = n0 + (lane & 15);
  int kb0 = (lane >> 4) * 8;

  f32x4 aR[4]  = {{0.f,0.f,0.f,0.f},{0.f,0.f,0.f,0.f},{0.f,0.f,0.f,0.f},{0.f,0.f,0.f,0.f}};
  f32x4 aZ[4]  = {{0.f,0.f,0.f,0.f},{0.f,0.f,0.f,0.f},{0.f,0.f,0.f,0.f},{0.f,0.f,0.f,0.f}};
  f32x4 aIN[4] = {{0.f,0.f,0.f,0.f},{0.f,0.f,0.f,0.f},{0.f,0.f,0.f,0.f},{0.f,0.f,0.f,0.f}};
  f32x4 aHN[4] = {{0.f,0.f,0.f,0.f},{0.f,0.f,0.f,0.f},{0.f,0.f,0.f,0.f},{0.f,0.f,0.f,0.f}};

  float dn = 1.f / fmaxf(cnt[row], 1.f);
  // ---- loop 1: A = m = rrelu(sbuf/dn + bias), W = Wih ----
  for (int k0 = 0; k0 < K; k0 += 32) {
    int kb = k0 + kb0;
    const float* ap = sbuf + (size_t)row * K + kb;
    float4 v0 = *(const float4*)ap, v1 = *(const float4*)(ap + 4);
    float4 b0 = *(const float4*)(mbias + kb), b1 = *(const float4*)(mbias + kb + 4);
    half8v af;
    af[0]=(f16)rrelu(v0.x*dn+b0.x); af[1]=(f16)rrelu(v0.y*dn+b0.y);
    af[2]=(f16)rrelu(v0.z*dn+b0.z); af[3]=(f16)rrelu(v0.w*dn+b0.w);
    af[4]=(f16)rrelu(v1.x*dn+b1.x); af[5]=(f16)rrelu(v1.y*dn+b1.y);
    af[6]=(f16)rrelu(v1.z*dn+b1.z); af[7]=(f16)rrelu(v1.w*dn+b1.w);
    #pragma unroll
    for (int jf = 0; jf < 4; jf++) {
      int wr = j0 + jf*16 + (lane & 15);
      half8v wR = *(const half8v*)(Wih + (size_t)wr*K + kb);
      half8v wZ = *(const half8v*)(Wih + (size_t)(H + wr)*K + kb);
      half8v wN = *(const half8v*)(Wih + (size_t)(2*H + wr)*K + kb);
      aR[jf]  = __builtin_amdgcn_mfma_f32_16x16x32_f16(af, wR, aR[jf], 0, 0, 0);
      aZ[jf]  = __builtin_amdgcn_mfma_f32_16x16x32_f16(af, wZ, aZ[jf], 0, 0, 0);
      aIN[jf] = __builtin_amdgcn_mfma_f32_16x16x32_f16(af, wN, aIN[jf], 0, 0, 0);
    }
  }
  // ---- loop 2: A = h, W = Whh ----
  for (int k0 = 0; k0 < K; k0 += 32) {
    int kb = k0 + kb0;
    const float* ap = hold + (size_t)row * K + kb;
    float4 v0 = *(const float4*)ap, v1 = *(const float4*)(ap + 4);
    half8v af;
    af[0]=(f16)v0.x; af[1]=(f16)v0.y; af[2]=(f16)v0.z; af[3]=(f16)v0.w;
    af[4]=(f16)v1.x; af[5]=(f16)v1.y; af[6]=(f16)v1.z; af[7]=(f16)v1.w;
    #pragma unroll
    for (int jf = 0; jf < 4; jf++) {
      int wr = j0 + jf*16 + (lane & 15);
      half8v wR = *(const half8v*)(Whh + (size_t)wr*K + kb);
      half8v wZ = *(const half8v*)(Whh + (size_t)(H + wr)*K + kb);
      half8v wN = *(const half8v*)(Whh + (size_t)(2*H + wr)*K + kb);
      aR[jf]  = __builtin_amdgcn_mfma_f32_16x16x32_f16(af, wR, aR[jf], 0, 0, 0);
      aZ[jf]  = __builtin_amdgcn_mfma_f32_16x16x32_f16(af, wZ, aZ[jf], 0, 0, 0);
      aHN[jf] = __builtin_amdgcn_mfma_f32_16x16x32_f16(af, wN, aHN[jf], 0, 0, 0);
    }
  }
  // ---- epilogue: GRU combine ----
  int r0 = n0 + ((lane >> 4) << 2);
  #pragma unroll
  for (int jf = 0; jf < 4; jf++) {
    int col = j0 + jf*16 + (lane & 15);
    float bR = bih[col] + bhh[col];
    float bZ = bih[H + col] + bhh[H + col];
    float bI = bih[2*H + col], bH = bhh[2*H + col];
    #pragma unroll
    for (int r = 0; r < 4; r++) {
      float rr = sigm(aR[jf][r] + bR);
      float zz = sigm(aZ[jf][r] + bZ);
      float nn = tanhf(aIN[jf][r] + bI + rr*(aHN[jf][r] + bH));
      float ho = hold[(size_t)(r0 + r)*H + col];
      hnew[(size_t)(r0 + r)*H + col] = (1.f - zz)*nn + zz*ho;
    }
  }
}

// ================= small kernels =================
__global__ void bn_stats_k(const float* __restrict__ X, int nrow, int F,
                           float* __restrict__ mean, float* __restrict__ var) {
  int f = blockIdx.x, t = threadIdx.x;
  __shared__ float s1[256], s2[256];
  float a = 0.f, b = 0.f;
  for (int n = t; n < nrow; n += 256) {
    float v = X[(size_t)n * F + f];
    a += v; b += v * v;
  }
  s1[t] = a; s2[t] = b; __syncthreads();
  for (int w = 128; w > 0; w >>= 1) {
    if (t < w) { s1[t] += s1[t+w]; s2[t] += s2[t+w]; }
    __syncthreads();
  }
  if (t == 0) {
    float m = s1[0] / (float)nrow;
    mean[f] = m;
    var[f]  = s2[0] / (float)nrow - m * m;
  }
}

// merged node + edge embed
__global__ void embed_k(const float* __restrict__ x,
                        const float* __restrict__ mean, const float* __restrict__ var,
                        const float* __restrict__ g, const float* __restrict__ b,
                        const float* __restrict__ Wn, const float* __restrict__ bnode,
                        float* __restrict__ nodeA,
                        const float* __restrict__ eattr,
                        const float* __restrict__ We, const float* __restrict__ be,
                        float* __restrict__ ea12) {
  if (blockIdx.x < 2048) {
    int idx = blockIdx.x * 256 + threadIdx.x;
    int n = idx >> 6, o = idx & 63;
    float acc = bnode[o];
    #pragma unroll
    for (int i = 0; i < 8; i++) {
      float xn = (x[n*8+i] - mean[i]) * rsqrtf(var[i] + BN_EPS) * g[i] + b[i];
      acc += xn * Wn[i*64 + o];
    }
    nodeA[idx] = rrelu(acc);
  } else {
    int idx = (blockIdx.x - 2048) * 256 + threadIdx.x;
    if (idx >= N_EDGES * 12) return;
    int e = idx / 12, j = idx - e * 12;
    float acc = be[j];
    #pragma unroll
    for (int k = 0; k < 19; k++) acc += eattr[e*19+k] * We[k*12 + j];
    ea12[idx] = rrelu(acc);
  }
}

// packs: f16 weights [J,K] + fp32 Wfold + zero cnt
__global__ void pack_k(const float* __restrict__ Wnn1,
                       const float* __restrict__ Wih1, const float* __restrict__ Whh1,
                       const float* __restrict__ Wc1,  const float* __restrict__ Wc2,
                       const float* __restrict__ Wnn2,
                       const float* __restrict__ Wih2, const float* __restrict__ Whh2,
                       const float* __restrict__ Ws_ih, const float* __restrict__ Ws_hh,
                       f16* __restrict__ Wz1h,
                       f16* __restrict__ Wih1h, f16* __restrict__ Whh1h,
                       f16* __restrict__ Wc1Th, f16* __restrict__ Wc2Th,
                       f16* __restrict__ W2fh,
                       f16* __restrict__ Wih2h, f16* __restrict__ Whh2h,
                       float* __restrict__ Wfold,
                       float* __restrict__ cnt1, float* __restrict__ cnt2) {
  int idx = blockIdx.x * 256 + threadIdx.x;
  if (idx < 49152) {  // Wz1h [768][64]: jj=k*64+o, i
    int jj = idx >> 6, i = idx & 63;
    int k = jj >> 6, o = jj & 63;
    Wz1h[idx] = (f16)Wnn1[k*4096 + i*64 + o];
  }
  if (idx < 12288) { Wih1h[idx] = (f16)Wih1[idx]; Whh1h[idx] = (f16)Whh1[idx]; }
  if (idx < 8192) {   // Wc1Th [128][64]
    int o = idx >> 6, i = idx & 63;
    Wc1Th[idx] = (f16)Wc1[i*128 + o];
  }
  if (idx < 16384) {  // Wc2Th [128][128]
    int o = idx >> 7, i = idx & 127;
    Wc2Th[idx] = (f16)Wc2[i*128 + o];
  }
  if (idx < 131072) { // W2fh [1024][128]: r=k*128+o, i
    int r = idx >> 7, i = idx & 127;
    int k = r >> 7, o = r & 127;
    W2fh[idx] = (f16)Wnn2[k*16384 + i*128 + o];
  }
  if (idx < 49152) { Wih2h[idx] = (f16)Wih2[idx]; Whh2h[idx] = (f16)Whh2[idx]; }
  if (idx < 131072) { // Wfold fp32 [256][512]
    int i = idx >> 9, j = idx & 511;
    float v = Ws_ih[(size_t)j*256 + i];
    if (i < 128) v += Ws_hh[(size_t)j*128 + i];
    Wfold[idx] = v;
  }
  if (idx < N_NODES) { cnt1[idx] = 0.f; cnt2[idx] = 0.f; }
}

// per-dst edge counts (iteration-invariant)
__global__ void cnt_k(const int* __restrict__ ei, const int* __restrict__ ei3,
                      float* __restrict__ cnt1, float* __restrict__ cnt2) {
  int idx = blockIdx.x * 256 + threadIdx.x;
  if (idx < N_EDGES) atomicAdd(&cnt1[ei[N_EDGES + idx]], 1.0f);
  if (idx < N_E3) {
    atomicAdd(&cnt2[ei3[N_E3 + idx]], 1.0f);
    atomicAdd(&cnt2[ei3[idx]], 1.0f);
  }
}

// conv1: msg[e,o] = sum_k ea[e,k] * Z[src, k*64+o]; scatter to sbuf
__global__ void conv1_msg_k(const float* __restrict__ Z, const int* __restrict__ ei,
                            const float* __restrict__ ea, float* __restrict__ sbuf) {
  int idx = blockIdx.x * 256 + threadIdx.x;
  if (idx >= N_EDGES * 64) return;
  int e = idx >> 6, o = idx & 63;
  int src = ei[e], dst = ei[N_EDGES + e];
  const float* z = Z + (size_t)src * 768 + o;
  float msg = 0.f;
  #pragma unroll
  for (int k = 0; k < 12; k++) msg += ea[e*12 + k] * z[k*64];
  atomicAdd(&sbuf[dst*64 + o], msg);
}

// conv2: msg[e,o] = sum_k ea3[e&1023,k] * Zg[e, k*128+o]; dst = ei3[(e+1024)&2047]
__global__ void conv2_msg_k(const float* __restrict__ Zg, const int* __restrict__ ei3,
                            const float* __restrict__ ea3, float* __restrict__ sbuf) {
  int idx = blockIdx.x * 256 + threadIdx.x;
  if (idx >= 2*N_E3*128) return;
  int e = idx >> 7, o = idx & 127;
  int eb = e & (N_E3 - 1);
  int dst = ei3[(e + N_E3) & (2*N_E3 - 1)];
  const float* z = Zg + (size_t)e*1024 + o;
  float msg = 0.f;
  #pragma unroll
  for (int k = 0; k < 8; k++) msg += ea3[eb*8 + k] * z[k*128];
  atomicAdd(&sbuf[dst*128 + o], msg);
}

// ---------- Set2Set: 1024 thr/graph, folded weights, step-0 shortcut, x in LDS ----------
__global__ __launch_bounds__(1024) void set2set_k(const float* __restrict__ x,
    const float* __restrict__ Wfold,
    const float* __restrict__ bs_ih, const float* __restrict__ bs_hh,
    float* __restrict__ qpool) {
  int g = blockIdx.x, t = threadIdx.x;
  __shared__ float xs[NPG*128];
  __shared__ float hr[256];
  __shared__ float cbuf[128];
  __shared__ float pbuf[1024];
  __shared__ float abuf[NPG];
  *(float4*)&xs[t*4] = *(const float4*)(x + (size_t)g*NPG*128 + t*4);
  if (t < 128) {
    float gi = bs_ih[t]     + bs_hh[t];
    float gg = bs_ih[256+t] + bs_hh[256+t];
    float go = bs_ih[384+t] + bs_hh[384+t];
    float c0 = sigm(gi) * tanhf(gg);
    cbuf[t] = c0;
    hr[t] = sigm(go) * tanhf(c0);
  }
  __syncthreads();
  #pragma unroll 1
  for (int step = 0; step < 3; step++) {
    {
      int node = t >> 5, s = t & 31;
      const float* xr = xs + node*128 + s*4;
      float p = xr[0]*hr[s*4] + xr[1]*hr[s*4+1] + xr[2]*hr[s*4+2] + xr[3]*hr[s*4+3];
      p += __shfl_down(p, 16, 32); p += __shfl_down(p, 8, 32);
      p += __shfl_down(p, 4, 32);  p += __shfl_down(p, 2, 32);
      p += __shfl_down(p, 1, 32);
      if (s == 0) pbuf[node] = p;
    }
    __syncthreads();
    if (t < NPG) {
      float e = pbuf[t];
      float mx = e;
      for (int o = 16; o > 0; o >>= 1) mx = fmaxf(mx, __shfl_xor(mx, o, 32));
      float ex = __expf(e - mx);
      float den = ex;
      for (int o = 16; o > 0; o >>= 1) den += __shfl_xor(den, o, 32);
      abuf[t] = ex / den;
    }
    __syncthreads();
    if (t < 128) {
      float r = 0.f;
      #pragma unroll 8
      for (int nn = 0; nn < NPG; nn++) r += abuf[nn] * xs[nn*128 + t];
      hr[128 + t] = r;
    }
    __syncthreads();
    if (step == 2) break;
    {
      int j = t & 511, half = t >> 9;
      const float* wp = Wfold + (size_t)(half*128)*512 + j;
      const float* iv = hr + half*128;
      float a0=0.f, a1=0.f, a2=0.f, a3=0.f;
      #pragma unroll 4
      for (int i = 0; i < 128; i += 4) {
        a0 += iv[i]   * wp[(i)  *512];
        a1 += iv[i+1] * wp[(i+1)*512];
        a2 += iv[i+2] * wp[(i+2)*512];
        a3 += iv[i+3] * wp[(i+3)*512];
      }
      pbuf[t] = a0 + a1 + a2 + a3;
    }
    __syncthreads();
    if (t < 128) {
      float gi = pbuf[t]     + pbuf[512+t] + bs_ih[t]     + bs_hh[t];
      float gf = pbuf[128+t] + pbuf[640+t] + bs_ih[128+t] + bs_hh[128+t];
      float gg = pbuf[256+t] + pbuf[768+t] + bs_ih[256+t] + bs_hh[256+t];
      float go = pbuf[384+t] + pbuf[896+t] + bs_ih[384+t] + bs_hh[384+t];
      float ci = sigm(gf) * cbuf[t] + sigm(gi) * tanhf(gg);
      cbuf[t] = ci;
      hr[t] = sigm(go) * tanhf(ci);
    }
    __syncthreads();
  }
  if (t < 256) qpool[g*256 + t] = hr[t];
}

__global__ void yhat_k(const float* __restrict__ feat, const int* __restrict__ ei3,
                       const int* __restrict__ batch, const float* __restrict__ qpool,
                       float* __restrict__ yhat) {
  int idx = blockIdx.x * blockDim.x + threadIdx.x;
  if (idx >= N_E3 * 640) return;
  int e = idx / 640, j = idx - e * 640;
  int s0 = ei3[e], s1 = ei3[N_E3 + e];
  float v;
  if (j < 128)      { v = 0.5f * (feat[s0*128+j] + feat[s1*128+j]); }
  else if (j < 256) { int jj = j-128; v = feat[s0*128+jj] * feat[s1*128+jj]; }
  else if (j < 384) { int jj = j-256; float d = feat[s0*128+jj] - feat[s1*128+jj]; v = d*d; }
  else              { int cbi = batch[s0]; v = qpool[cbi*256 + (j-384)]; }
  yhat[idx] = v;
}

__global__ void final_k(const float* __restrict__ yhat,
                        const float* __restrict__ mean, const float* __restrict__ var,
                        const float* __restrict__ g, const float* __restrict__ b,
                        const float* __restrict__ ea3,
                        const float* __restrict__ Ww, const float* __restrict__ Wb,
                        float* __restrict__ out) {
  int e = blockIdx.x, t = threadIdx.x;
  __shared__ float red[128];
  float av[8];
  #pragma unroll
  for (int k = 0; k < 8; k++) av[k] = ea3[e*8 + k];
  float acc = 0.f;
  for (int j = t; j < 640; j += 128) {
    float yn = (yhat[(size_t)e*640 + j] - mean[j]) * rsqrtf(var[j] + BN_EPS) * g[j] + b[j];
    float wj = 0.f;
    #pragma unroll
    for (int k = 0; k < 8; k++) wj += av[k] * Ww[k*640 + j];
    acc += yn * wj;
  }
  red[t] = acc; __syncthreads();
  for (int w = 64; w > 0; w >>= 1) {
    if (t < w) red[t] += red[t+w];
    __syncthreads();
  }
  if (t == 0) {
    float bb = 0.f;
    #pragma unroll
    for (int k = 0; k < 8; k++) bb += av[k] * Wb[k];
    out[e] = red[0] + bb;
  }
}

extern "C" void kernel_launch(void* const* d_in, const int* in_sizes, int n_in,
                              void* d_out, int out_size, void* d_ws, size_t ws_size,
                              hipStream_t stream) {
  const float* x      = (const float*)d_in[0];
  const int*   ei     = (const int*)  d_in[1];
  const float* eattr  = (const float*)d_in[2];
  const int*   ei3    = (const int*)  d_in[3];
  const float* ea3    = (const float*)d_in[4];
  const int*   batch  = (const int*)  d_in[5];
  const float* bnx_g  = (const float*)d_in[6];
  const float* bnx_b  = (const float*)d_in[7];
  const float* Wn     = (const float*)d_in[8];
  const float* bnode  = (const float*)d_in[9];
  const float* We     = (const float*)d_in[10];
  const float* be     = (const float*)d_in[11];
  const float* Wnn1   = (const float*)d_in[12];
  const float* bias1  = (const float*)d_in[13];
  const float* Wih1   = (const float*)d_in[14];
  const float* Whh1   = (const float*)d_in[15];
  const float* bih1   = (const float*)d_in[16];
  const float* bhh1   = (const float*)d_in[17];
  const float* bnc_g  = (const float*)d_in[18];
  const float* bnc_b  = (const float*)d_in[19];
  const float* Wc1    = (const float*)d_in[20];
  const float* bc1    = (const float*)d_in[21];
  const float* Wc2    = (const float*)d_in[22];
  const float* bc2    = (const float*)d_in[23];
  const float* Wnn2   = (const float*)d_in[24];
  const float* bias2  = (const float*)d_in[25];
  const float* Wih2   = (const float*)d_in[26];
  const float* Whh2   = (const float*)d_in[27];
  const float* bih2   = (const float*)d_in[28];
  const float* bhh2   = (const float*)d_in[29];
  const float* Ws_ih  = (const float*)d_in[30];
  const float* Ws_hh  = (const float*)d_in[31];
  const float* bs_ih  = (const float*)d_in[32];
  const float* bs_hh  = (const float*)d_in[33];
  const float* bno_g  = (const float*)d_in[34];
  const float* bno_b  = (const float*)d_in[35];
  const float* Ww     = (const float*)d_in[36];
  const float* Wb     = (const float*)d_in[37];
  float* out = (float*)d_out;

  // workspace carve-up (ws ~256 MiB per fillBuffer evidence; we use ~48 MB)
  float* W = (float*)d_ws;
  size_t off = 0;
  float* Wfold  = W + off; off += 131072;                 // [256][512] fp32
  float* ea12   = W + off; off += (size_t)N_EDGES * 12;
  float* nodeA  = W + off; off += (size_t)N_NODES * 64;
  float* nodeA2 = W + off; off += (size_t)N_NODES * 64;
  float* sbuf   = W + off; off += (size_t)N_NODES * 128;
  float* cnt1   = W + off; off += (size_t)N_NODES;
  float* cnt2   = W + off; off += (size_t)N_NODES;
  float* y1     = W + off; off += (size_t)N_NODES * 128;
  float* nodeB  = W + off; off += (size_t)N_NODES * 128;
  float* nodeB2 = W + off; off += (size_t)N_NODES * 128;
  float* Z      = W + off; off += (size_t)N_NODES * 768;  // aliased: Zg [2048][1024]
  float* qpool  = W + off; off += (size_t)NGRAPH * 256;
  float* yhat   = W + off; off += (size_t)N_E3 * 640;
  float* mean   = W + off; off += 640;
  float* var    = W + off; off += 640;
  // f16 weight packs
  f16* F = (f16*)(W + off);
  size_t foff = 0;
  f16* Wz1h  = F + foff; foff += 49152;    // [768][64]
  f16* Wih1h = F + foff; foff += 12288;    // [192][64]
  f16* Whh1h = F + foff; foff += 12288;
  f16* Wc1Th = F + foff; foff += 8192;     // [128][64]
  f16* Wc2Th = F + foff; foff += 16384;    // [128][128]
  f16* W2fh  = F + foff; foff += 131072;   // [1024][128]
  f16* Wih2h = F + foff; foff += 49152;    // [384][128]
  f16* Whh2h = F + foff; foff += 49152;
  (void)foff; (void)ws_size; (void)in_sizes; (void)n_in; (void)out_size;

  float* Zg = Z;   // [2048][1024]

  // 0. one-time packs (+ zero cnt) + counts
  pack_k<<<512, 256, 0, stream>>>(Wnn1, Wih1, Whh1, Wc1, Wc2, Wnn2, Wih2, Whh2, Ws_ih, Ws_hh,
                                  Wz1h, Wih1h, Whh1h, Wc1Th, Wc2Th, W2fh, Wih2h, Whh2h,
                                  Wfold, cnt1, cnt2);
  cnt_k<<<(N_EDGES+255)/256, 256, 0, stream>>>(ei, ei3, cnt1, cnt2);

  // 1. embeds
  bn_stats_k<<<8, 256, 0, stream>>>(x, N_NODES, 8, mean, var);
  embed_k<<<2048 + 768, 256, 0, stream>>>(x, mean, var, bnx_g, bnx_b, Wn, bnode, nodeA,
                                          eattr, We, be, ea12);

  // 2. layer-1 x2: Z MFMA (+zero sbuf) -> scatter -> fused GRU (ping-pong)
  {
    float* s0 = nodeA; float* s1 = nodeA2;
    for (int it = 0; it < 2; it++) {
      mgemm_k<0,0><<<1536 + 16, 256, 0, stream>>>(s0, Wz1h, nullptr,
          nullptr, nullptr, nullptr, nullptr, nullptr, Z, N_NODES, 64, 768,
          1536, sbuf, N_NODES*64);
      conv1_msg_k<<<(N_EDGES*64)/256, 256, 0, stream>>>(Z, ei, ea12, sbuf);
      gruf_k<6><<<256, 128, 0, stream>>>(sbuf, cnt1, bias1, Wih1h, Whh1h, bih1, bhh1, s0, s1);
      float* tmp = s0; s0 = s1; s1 = tmp;
    }
    // final layer-1 state is back in nodeA
  }

  // 3. BN (fused) + FC1 + FC2 (MFMA)
  bn_stats_k<<<64, 256, 0, stream>>>(nodeA, N_NODES, 64, mean, var);
  mgemm_k<2,1><<<256, 256, 0, stream>>>(nodeA, Wc1Th, bc1,
      mean, var, bnc_g, bnc_b, nullptr, y1, N_NODES, 64, 128, 256, nullptr, 0);
  mgemm_k<0,1><<<256, 256, 0, stream>>>(y1, Wc2Th, bc2,
      nullptr, nullptr, nullptr, nullptr, nullptr, nodeB, N_NODES, 128, 128, 256, nullptr, 0);

  // 4. layer-2 x2: Zg MFMA (row-gather, +zero sbuf) -> scatter -> fused GRU (ping-pong)
  {
    float* s0 = nodeB; float* s1 = nodeB2;
    for (int it = 0; it < 2; it++) {
      mgemm_k<0,0><<<512 + 16, 256, 0, stream>>>(s0, W2fh, nullptr,
          nullptr, nullptr, nullptr, nullptr, ei3, Zg, 2*N_E3, 128, 1024,
          512, sbuf, N_NODES*128);
      conv2_msg_k<<<(2*N_E3*128)/256, 256, 0, stream>>>(Zg, ei3, ea3, sbuf);
      gruf_k<7><<<256, 256, 0, stream>>>(sbuf, cnt2, bias2, Wih2h, Whh2h, bih2, bhh2, s0, s1);
      float* tmp = s0; s0 = s1; s1 = tmp;
    }
    // final layer-2 state is back in nodeB
  }

  // 5. set2set
  set2set_k<<<NGRAPH, 1024, 0, stream>>>(nodeB, Wfold, bs_ih, bs_hh, qpool);

  // 6. yhat + BN + weighted sum
  yhat_k<<<(N_E3*640 + 255)/256, 256, 0, stream>>>(nodeB, ei3, batch, qpool, yhat);
  bn_stats_k<<<640, 256, 0, stream>>>(yhat, N_E3, 640, mean, var);
  final_k<<<N_E3, 128, 0, stream>>>(yhat, mean, var, bno_g, bno_b, ea3, Ww, Wb, out);
}